// Round 3
// baseline (1669.708 us; speedup 1.0000x reference)
//
#include <hip/hip_runtime.h>
#include <hip/hip_bf16.h>

#define B_    32
#define L_    512
#define D_    192
#define DEPTH_ 12
#define H_    6
#define DH_   32
#define NR    (B_*L_)   // 16384 rows

typedef unsigned short u16;
typedef __attribute__((ext_vector_type(8))) short short8;   // 8 bf16 in 4 VGPRs
typedef __attribute__((ext_vector_type(4))) float f32x4;

__device__ __forceinline__ float b2f(u16 u){ union{unsigned int i; float f;} v; v.i=((unsigned)u)<<16; return v.f; }
__device__ __forceinline__ u16 f2b(float f){ __hip_bfloat16 h = __float2bfloat16(f); return *reinterpret_cast<u16*>(&h); }

// async global->LDS, 16B per lane; LDS dest = wave-uniform base + lane*16
__device__ __forceinline__ void gll16(const u16* g, u16* l){
    __builtin_amdgcn_global_load_lds((const __attribute__((address_space(1))) unsigned int*)g,
                                     (__attribute__((address_space(3))) unsigned int*)l, 16, 0, 0);
}

// ---------------- f32 -> bf16 conversion (4 elems/thread) ----------------
__global__ __launch_bounds__(256) void k_cvt(const float* __restrict__ src, u16* __restrict__ dst, int n4){
    int i = blockIdx.x*256 + threadIdx.x;
    if (i >= n4) return;
    float4 v = reinterpret_cast<const float4*>(src)[i];
    ushort4 o; o.x=f2b(v.x); o.y=f2b(v.y); o.z=f2b(v.z); o.w=f2b(v.w);
    reinterpret_cast<ushort4*>(dst)[i] = o;
}

// ---------------- embedding ----------------
__global__ void k_embed(const int* __restrict__ seq, const float* __restrict__ emb, float* __restrict__ x){
    int i = blockIdx.x*blockDim.x + threadIdx.x;
    if (i >= NR*D_) return;
    int row = i / D_; int d = i - row*D_;
    x[i] = emb[seq[row]*D_ + d];
}

// ---------------- LayerNorm: one wave per row, f32 in -> bf16 out ------
__global__ __launch_bounds__(256) void k_ln(const float* __restrict__ x, const float* __restrict__ s,
                                            const float* __restrict__ b, u16* __restrict__ h){
    int row  = blockIdx.x*4 + (threadIdx.x>>6);
    int lane = threadIdx.x & 63;
    const float* xr = x + (size_t)row*D_;
    float v0=xr[lane], v1=xr[lane+64], v2=xr[lane+128];
    float sum = v0+v1+v2;
    #pragma unroll
    for(int off=32; off; off>>=1) sum += __shfl_xor(sum, off);
    float mu = sum * (1.f/192.f);
    float d0=v0-mu, d1=v1-mu, d2=v2-mu;
    float vs = d0*d0+d1*d1+d2*d2;
    #pragma unroll
    for(int off=32; off; off>>=1) vs += __shfl_xor(vs, off);
    float rstd = rsqrtf(vs*(1.f/192.f) + 1e-5f);
    u16* hr = h + (size_t)row*D_;
    hr[lane]     = f2b(d0*rstd*s[lane]     + b[lane]);
    hr[lane+64]  = f2b(d1*rstd*s[lane+64]  + b[lane+64]);
    hr[lane+128] = f2b(d2*rstd*s[lane+128] + b[lane+128]);
}

// ---------------- GEMM: C = A(M,K) @ W(N,K)^T + bias ----------------
// 128x64 tile, 256 thr (4 waves 2x2), BK=64. global_load_lds staging with XOR swizzle:
// element (r,k) stored at r*64 + ((k>>3)^(r&7))*8 + (k&7); lane L fetches gseg = (L&7)^(r&7).
template<int EPI>   // 0=store bf16, 1=GELU->bf16, 2=residual add f32
__global__ __launch_bounds__(256) void k_gemm(const u16* __restrict__ A, const u16* __restrict__ W,
                                              const float* __restrict__ bias,
                                              u16* __restrict__ out, float* __restrict__ xres,
                                              int M, int N, int K){
    __shared__ __align__(16) u16 As[128*64];
    __shared__ __align__(16) u16 Ws[64*64];
    int tid = threadIdx.x;
    int n0 = blockIdx.x*64, m0 = blockIdx.y*128;
    int w = tid>>6, lane = tid&63, quad = lane>>4, l16 = lane&15;
    int wm = w>>1, wn = w&1;
    int wbase = tid & ~63;
    f32x4 zero = {0.f,0.f,0.f,0.f};
    f32x4 acc[4][2];
    #pragma unroll
    for(int a=0;a<4;a++){ acc[a][0]=zero; acc[a][1]=zero; }
    int nchunks = K>>6;
    for(int kc=0; kc<nchunks; kc++){
        int kbase = kc<<6;
        #pragma unroll
        for(int i=0;i<4;i++){
            int L = tid + (i<<8);
            int r = L>>3;
            int gseg = (L&7) ^ (r&7);
            gll16(&A[(size_t)(m0+r)*K + kbase + gseg*8], &As[(size_t)(wbase + (i<<8))*8]);
        }
        #pragma unroll
        for(int i=0;i<2;i++){
            int L = tid + (i<<8);
            int r = L>>3;
            int gseg = (L&7) ^ (r&7);
            gll16(&W[(size_t)(n0+r)*K + kbase + gseg*8], &Ws[(size_t)(wbase + (i<<8))*8]);
        }
        __syncthreads();
        #pragma unroll
        for(int kk=0; kk<64; kk+=32){
            int sw = ((kk>>3) + quad) ^ (l16&7);   // row&7 == l16&7 for all fragment rows
            short8 af[4], bf[2];
            #pragma unroll
            for(int mi=0;mi<4;mi++) af[mi] = *reinterpret_cast<const short8*>(&As[(wm*64+mi*16+l16)*64 + sw*8]);
            #pragma unroll
            for(int ni=0;ni<2;ni++) bf[ni] = *reinterpret_cast<const short8*>(&Ws[(wn*32+ni*16+l16)*64 + sw*8]);
            #pragma unroll
            for(int mi=0;mi<4;mi++)
                #pragma unroll
                for(int ni=0;ni<2;ni++)
                    acc[mi][ni] = __builtin_amdgcn_mfma_f32_16x16x32_bf16(af[mi], bf[ni], acc[mi][ni], 0,0,0);
        }
        __syncthreads();
    }
    #pragma unroll
    for(int mi=0;mi<4;mi++){
        int row = m0 + wm*64 + mi*16 + quad*4;
        #pragma unroll
        for(int ni=0;ni<2;ni++){
            int col = n0 + wn*32 + ni*16 + l16;
            float bv = bias[col];
            #pragma unroll
            for(int r=0;r<4;r++){
                float v = acc[mi][ni][r] + bv;
                if (EPI==0){
                    out[(size_t)(row+r)*N + col] = f2b(v);
                } else if (EPI==1){
                    float g = 0.5f*v*(1.f + erff(v*0.70710678f));
                    out[(size_t)(row+r)*N + col] = f2b(g);
                } else {
                    xres[(size_t)(row+r)*D_ + col] += v;
                }
            }
        }
    }
}

// ---------------- V transpose: vt[b][h][dh][k] <- qkv[b,k,384+h*32+dh] ----------------
__global__ __launch_bounds__(256) void k_vt(const u16* __restrict__ qkv, u16* __restrict__ vt){
    __shared__ u16 t[128*34];
    int b = blockIdx.z, h = blockIdx.y, kb = blockIdx.x*128;
    int tid = threadIdx.x;
    #pragma unroll
    for(int ld=0; ld<2; ld++){
        int idx = tid + (ld<<8); int kr = idx>>2, seg = idx&3;
        *reinterpret_cast<uint4*>(&t[kr*34 + seg*8]) =
            *reinterpret_cast<const uint4*>(&qkv[(size_t)(b*L_ + kb + kr)*576 + 384 + h*32 + seg*8]);
    }
    __syncthreads();
    #pragma unroll
    for(int st=0; st<2; st++){
        int idx = tid + (st<<8); int dh = idx>>4, sk = idx&15;
        u16 tmp[8];
        #pragma unroll
        for(int j=0;j<8;j++) tmp[j] = t[(sk*8+j)*34 + dh];
        *reinterpret_cast<uint4*>(&vt[(size_t)((b*H_+h)*32 + dh)*512 + kb + sk*8]) =
            *reinterpret_cast<uint4*>(tmp);
    }
}

// ---------------- flash attention: barrier-free, single-pass exp (no max shift) -------------
// block = (b,h,q-tile 64), 4 waves x 16 q-rows. K/V fragments direct from global (L1/L2-hot).
__global__ __launch_bounds__(256) void k_attn(const u16* __restrict__ qkv, const u16* __restrict__ vt,
                                              const u16* __restrict__ bppm16,
                                              const float* __restrict__ pair_w, const float* __restrict__ pair_b,
                                              const float* __restrict__ relw, const float* __restrict__ relb,
                                              u16* __restrict__ o){
    __shared__ u16 PsW[4][16*72];     // per-wave P round-trip
    __shared__ u16 biasW[4][16*72];   // per-wave bppm tile (16 q rows x 64 k)
    __shared__ float relE[4][72];     // per-wave rel LUT (exp2 domain, pair_b+relb folded)
    int tid = threadIdx.x;
    int blk = blockIdx.x;
    int b = blk/(H_*8); int rem = blk - b*(H_*8); int h = rem>>3; int qt = rem&7;
    int q0 = qt*64;
    int w = tid>>6, lane = tid&63, quad = lane>>4, l16 = lane&15;
    const float LOG2E = 1.4426950408889634f;
    float pwE  = pair_w[h]*LOG2E;
    float addE = (pair_b[h] + relb[h])*LOG2E;
    relE[w][lane] = relw[h*65 + lane]*LOG2E + addE;
    if (lane==0) relE[w][64] = relw[h*65 + 64]*LOG2E + addE;
    const float scaleE = 0.17677669529663687f*LOG2E;   // 1/sqrt(32) * log2(e)
    short8 qf = *reinterpret_cast<const short8*>(&qkv[(size_t)(b*L_ + q0 + w*16 + l16)*576 + h*32 + quad*8]);
    f32x4 zero = {0.f,0.f,0.f,0.f};
    f32x4 accO[2]; accO[0]=zero; accO[1]=zero;
    float l_acc[4] = {0.f,0.f,0.f,0.f};
    for(int kt=0; kt<8; kt++){
        int k0 = kt*64;
        // stage bppm tile (per wave, rows = this wave's 16 q rows)
        uint4 bt[2];
        #pragma unroll
        for(int ld=0; ld<2; ld++){
            int idx = lane + (ld<<6); int row = idx>>3, seg = idx&7;
            bt[ld] = *reinterpret_cast<const uint4*>(&bppm16[(size_t)(b*L_ + q0 + w*16 + row)*512 + k0 + seg*8]);
        }
        // S = Q K^T  (K fragments direct from global)
        f32x4 sv[4];
        #pragma unroll
        for(int ni=0; ni<4; ni++){
            short8 kf = *reinterpret_cast<const short8*>(&qkv[(size_t)(b*L_ + k0 + ni*16 + l16)*576 + 192 + h*32 + quad*8]);
            sv[ni] = __builtin_amdgcn_mfma_f32_16x16x32_bf16(qf, kf, zero, 0,0,0);
        }
        #pragma unroll
        for(int ld=0; ld<2; ld++){
            int idx = lane + (ld<<6); int row = idx>>3, seg = idx&7;
            *reinterpret_cast<uint4*>(&biasW[w][row*72 + seg*8]) = bt[ld];
        }
        bool far = (qt-kt>=2) | (kt-qt>=2);
        float relc = relE[w][qt>kt ? 64 : 0];
        // p = exp2(s*scaleE + bppm*pwE + relE[clip(q-k)]), accumulate l from ROUNDED p
        #pragma unroll
        for(int ni=0; ni<4; ni++){
            #pragma unroll
            for(int r=0; r<4; r++){
                float bb = b2f(biasW[w][(quad*4+r)*72 + ni*16 + l16]);
                float relv;
                if (far) relv = relc;
                else {
                    int dlt = (q0 + w*16 + quad*4 + r) - (k0 + ni*16 + l16);
                    dlt = dlt < -32 ? -32 : (dlt > 32 ? 32 : dlt);
                    relv = relE[w][dlt + 32];
                }
                float arg = fmaf(sv[ni][r], scaleE, fmaf(bb, pwE, relv));
                float pe = exp2f(arg);
                u16 pr = f2b(pe);
                PsW[w][(quad*4+r)*72 + ni*16 + l16] = pr;
                l_acc[r] += b2f(pr);
            }
        }
        // O += P V  (P via per-wave LDS round-trip into A-layout; V direct from global vt)
        #pragma unroll
        for(int kk=0; kk<64; kk+=32){
            short8 pf = *reinterpret_cast<const short8*>(&PsW[w][l16*72 + kk + quad*8]);
            #pragma unroll
            for(int t=0;t<2;t++){
                short8 vf = *reinterpret_cast<const short8*>(&vt[(size_t)((b*H_+h)*32 + t*16 + l16)*512 + k0 + kk + quad*8]);
                accO[t] = __builtin_amdgcn_mfma_f32_16x16x32_bf16(pf, vf, accO[t], 0,0,0);
            }
        }
    }
    // reduce l across the 16 l16 lanes (butterfly stays within quad group)
    #pragma unroll
    for(int r=0;r<4;r++){
        #pragma unroll
        for(int off=1; off<16; off<<=1) l_acc[r] += __shfl_xor(l_acc[r], off);
    }
    #pragma unroll
    for(int t=0;t<2;t++)
        #pragma unroll
        for(int r=0;r<4;r++){
            int qg = q0 + w*16 + quad*4 + r;
            o[(size_t)(b*L_ + qg)*D_ + h*32 + t*16 + l16] = f2b(accO[t][r] / l_acc[r]);
        }
}

// ---------------- final projection ----------------
__global__ __launch_bounds__(256) void k_proj(const float* __restrict__ x, const float* __restrict__ pw,
                                              const float* __restrict__ pb, float* __restrict__ out){
    int row  = blockIdx.x*4 + (threadIdx.x>>6);
    int lane = threadIdx.x & 63;
    const float* xr = x + (size_t)row*D_;
    float s0=0.f, s1=0.f;
    #pragma unroll
    for(int j=0;j<3;j++){
        float xv = xr[lane + 64*j];
        s0 += xv * pw[lane + 64*j];
        s1 += xv * pw[192 + lane + 64*j];
    }
    #pragma unroll
    for(int off=32; off; off>>=1){ s0 += __shfl_xor(s0, off); s1 += __shfl_xor(s1, off); }
    if (lane==0){
        out[(size_t)row*2 + 0] = s0 + pb[0];
        out[(size_t)row*2 + 1] = s1 + pb[1];
    }
}

extern "C" void kernel_launch(void* const* d_in, const int* in_sizes, int n_in,
                              void* d_out, int out_size, void* d_ws, size_t ws_size,
                              hipStream_t stream){
    const int*   seq    = (const int*)d_in[0];
    const float* bppm   = (const float*)d_in[2];
    const float* emb    = (const float*)d_in[3];
    const float* pair_w = (const float*)d_in[4];
    const float* pair_b = (const float*)d_in[5];
    const float* relw   = (const float*)d_in[6];
    const float* relb   = (const float*)d_in[7];
    const float* ln1s   = (const float*)d_in[8];
    const float* ln1b   = (const float*)d_in[9];
    const float* qkvw   = (const float*)d_in[10];
    const float* qkvb   = (const float*)d_in[11];
    const float* outw   = (const float*)d_in[12];
    const float* outb   = (const float*)d_in[13];
    const float* ln2s   = (const float*)d_in[14];
    const float* ln2b   = (const float*)d_in[15];
    const float* ff1w   = (const float*)d_in[16];
    const float* ff1b   = (const float*)d_in[17];
    const float* ff2w   = (const float*)d_in[18];
    const float* ff2b   = (const float*)d_in[19];
    const float* projw  = (const float*)d_in[20];
    const float* projb  = (const float*)d_in[21];

    char* ws = (char*)d_ws;
    float* x   = (float*)ws;  ws += (size_t)NR*D_*4;     // f32 residual
    u16*  h    = (u16*)ws;    ws += (size_t)NR*D_*2;     // LN out
    u16*  qkv  = (u16*)ws;    ws += (size_t)NR*576*2;
    u16*  o    = (u16*)ws;    ws += (size_t)NR*D_*2;
    u16*  ff   = (u16*)ws;    ws += (size_t)NR*768*2;
    u16* qkvw_h = (u16*)ws;   ws += (size_t)DEPTH_*576*D_*2;
    u16* outw_h = (u16*)ws;   ws += (size_t)DEPTH_*D_*D_*2;
    u16* ff1w_h = (u16*)ws;   ws += (size_t)DEPTH_*768*D_*2;
    u16* ff2w_h = (u16*)ws;   ws += (size_t)DEPTH_*D_*768*2;
    u16* bppm16 = (u16*)ws;   ws += (size_t)B_*L_*L_*2;  // 16.8 MB
    u16* vt     = (u16*)ws;   ws += (size_t)B_*H_*DH_*L_*2; // 6.3 MB

    {
        int n;
        n = DEPTH_*576*D_/4; k_cvt<<<(n+255)/256, 256, 0, stream>>>(qkvw, qkvw_h, n);
        n = DEPTH_*D_*D_/4;  k_cvt<<<(n+255)/256, 256, 0, stream>>>(outw, outw_h, n);
        n = DEPTH_*768*D_/4; k_cvt<<<(n+255)/256, 256, 0, stream>>>(ff1w, ff1w_h, n);
        n = DEPTH_*D_*768/4; k_cvt<<<(n+255)/256, 256, 0, stream>>>(ff2w, ff2w_h, n);
        n = B_*L_*L_/4;      k_cvt<<<(n+255)/256, 256, 0, stream>>>(bppm, bppm16, n);
    }

    k_embed<<<(NR*D_+255)/256, 256, 0, stream>>>(seq, emb, x);
    for(int i=0;i<DEPTH_;i++){
        k_ln<<<NR/4, 256, 0, stream>>>(x, ln1s+i*D_, ln1b+i*D_, h);
        k_gemm<0><<<dim3(576/64, NR/128), 256, 0, stream>>>(h, qkvw_h+(size_t)i*576*D_, qkvb+i*576, qkv, nullptr, NR, 576, D_);
        k_vt<<<dim3(4, H_, B_), 256, 0, stream>>>(qkv, vt);
        k_attn<<<B_*H_*8, 256, 0, stream>>>(qkv, vt, bppm16, pair_w, pair_b, relw, relb, o);
        k_gemm<2><<<dim3(192/64, NR/128), 256, 0, stream>>>(o, outw_h+(size_t)i*D_*D_, outb+i*D_, nullptr, x, NR, D_, D_);
        k_ln<<<NR/4, 256, 0, stream>>>(x, ln2s+i*D_, ln2b+i*D_, h);
        k_gemm<1><<<dim3(768/64, NR/128), 256, 0, stream>>>(h, ff1w_h+(size_t)i*768*D_, ff1b+i*768, ff, nullptr, NR, 768, D_);
        k_gemm<2><<<dim3(192/64, NR/128), 256, 0, stream>>>(ff, ff2w_h+(size_t)i*D_*768, ff2b+i*D_, nullptr, x, NR, D_, 768);
    }
    k_proj<<<NR/4, 256, 0, stream>>>(x, projw, projb, (float*)d_out);
}

// Round 4
// 1651.629 us; speedup vs baseline: 1.0109x; 1.0109x over previous
//
#include <hip/hip_runtime.h>
#include <hip/hip_bf16.h>

#define B_    32
#define L_    512
#define D_    192
#define DEPTH_ 12
#define H_    6
#define DH_   32
#define NR    (B_*L_)   // 16384 rows

typedef unsigned short u16;
typedef __attribute__((ext_vector_type(8))) short short8;   // 8 bf16 in 4 VGPRs
typedef __attribute__((ext_vector_type(4))) float f32x4;

__device__ __forceinline__ float b2f(u16 u){ union{unsigned int i; float f;} v; v.i=((unsigned)u)<<16; return v.f; }
__device__ __forceinline__ u16 f2b(float f){ __hip_bfloat16 h = __float2bfloat16(f); return *reinterpret_cast<u16*>(&h); }
__device__ __forceinline__ float b2f_lo(unsigned dw){ union{unsigned int i; float f;} v; v.i=dw<<16; return v.f; }
__device__ __forceinline__ float b2f_hi(unsigned dw){ union{unsigned int i; float f;} v; v.i=dw&0xffff0000u; return v.f; }

// async global->LDS, 16B per lane; LDS dest = wave-uniform base + lane*16
__device__ __forceinline__ void gll16(const u16* g, u16* l){
    __builtin_amdgcn_global_load_lds((const __attribute__((address_space(1))) unsigned int*)g,
                                     (__attribute__((address_space(3))) unsigned int*)l, 16, 0, 0);
}

// ---------------- f32 -> bf16 conversion (4 elems/thread) ----------------
__global__ __launch_bounds__(256) void k_cvt(const float* __restrict__ src, u16* __restrict__ dst, int n4){
    int i = blockIdx.x*256 + threadIdx.x;
    if (i >= n4) return;
    float4 v = reinterpret_cast<const float4*>(src)[i];
    ushort4 o; o.x=f2b(v.x); o.y=f2b(v.y); o.z=f2b(v.z); o.w=f2b(v.w);
    reinterpret_cast<ushort4*>(dst)[i] = o;
}

// ---------------- bppm permute: bp[b][qt][w][kt][lane][j=ni*4+r] = bf16(bppm[b, q, k]) --------
// q = qt*64 + w*16 + (lane>>4)*4 + r ; k = kt*64 + ni*16 + (lane&15)
__global__ __launch_bounds__(256) void k_bprep(const float* __restrict__ bppm, u16* __restrict__ bp){
    int tid = threadIdx.x; int w = tid>>6, lane = tid&63, quad = lane>>4, l16 = lane&15;
    int blk = blockIdx.x; int b = blk>>6, qt = (blk>>3)&7, kt = blk&7;
    const float* src = bppm + (size_t)(b*L_ + qt*64 + w*16 + quad*4)*L_ + kt*64 + l16;
    u16 vals[16];
    #pragma unroll
    for(int ni=0;ni<4;ni++)
        #pragma unroll
        for(int r=0;r<4;r++)
            vals[ni*4+r] = f2b(src[(size_t)r*L_ + ni*16]);
    u16* dst = bp + ((size_t)((((b*8+qt)*4+w)*8+kt)*64 + lane))*16;
    *reinterpret_cast<uint4*>(dst)   = *reinterpret_cast<uint4*>(vals);
    *reinterpret_cast<uint4*>(dst+8) = *reinterpret_cast<uint4*>(vals+8);
}

// ---------------- embedding ----------------
__global__ void k_embed(const int* __restrict__ seq, const float* __restrict__ emb, float* __restrict__ x){
    int i = blockIdx.x*blockDim.x + threadIdx.x;
    if (i >= NR*D_) return;
    int row = i / D_; int d = i - row*D_;
    x[i] = emb[seq[row]*D_ + d];
}

// ---------------- LayerNorm: one wave per row, f32 in -> bf16 out ------
__global__ __launch_bounds__(256) void k_ln(const float* __restrict__ x, const float* __restrict__ s,
                                            const float* __restrict__ b, u16* __restrict__ h){
    int row  = blockIdx.x*4 + (threadIdx.x>>6);
    int lane = threadIdx.x & 63;
    const float* xr = x + (size_t)row*D_;
    float v0=xr[lane], v1=xr[lane+64], v2=xr[lane+128];
    float sum = v0+v1+v2;
    #pragma unroll
    for(int off=32; off; off>>=1) sum += __shfl_xor(sum, off);
    float mu = sum * (1.f/192.f);
    float d0=v0-mu, d1=v1-mu, d2=v2-mu;
    float vs = d0*d0+d1*d1+d2*d2;
    #pragma unroll
    for(int off=32; off; off>>=1) vs += __shfl_xor(vs, off);
    float rstd = rsqrtf(vs*(1.f/192.f) + 1e-5f);
    u16* hr = h + (size_t)row*D_;
    hr[lane]     = f2b(d0*rstd*s[lane]     + b[lane]);
    hr[lane+64]  = f2b(d1*rstd*s[lane+64]  + b[lane+64]);
    hr[lane+128] = f2b(d2*rstd*s[lane+128] + b[lane+128]);
}

// ---------------- GEMM: C = A(M,K) @ W(N,K)^T + bias ----------------
// 128x64 tile, 256 thr (4 waves 2x2), BK=64. global_load_lds staging with XOR swizzle.
// EPI: 1=GELU->bf16, 2=residual add f32, 3=qkv store (cols<384) + fused V-transpose (cols>=384)
template<int EPI>
__global__ __launch_bounds__(256) void k_gemm(const u16* __restrict__ A, const u16* __restrict__ W,
                                              const float* __restrict__ bias,
                                              u16* __restrict__ out, float* __restrict__ xres,
                                              u16* __restrict__ vt,
                                              int M, int N, int K){
    __shared__ __align__(16) u16 As[128*64];
    __shared__ __align__(16) u16 Ws[64*64];
    int tid = threadIdx.x;
    int n0 = blockIdx.x*64, m0 = blockIdx.y*128;
    int w = tid>>6, lane = tid&63, quad = lane>>4, l16 = lane&15;
    int wm = w>>1, wn = w&1;
    int wbase = tid & ~63;
    f32x4 zero = {0.f,0.f,0.f,0.f};
    f32x4 acc[4][2];
    #pragma unroll
    for(int a=0;a<4;a++){ acc[a][0]=zero; acc[a][1]=zero; }
    int nchunks = K>>6;
    for(int kc=0; kc<nchunks; kc++){
        int kbase = kc<<6;
        #pragma unroll
        for(int i=0;i<4;i++){
            int L = tid + (i<<8);
            int r = L>>3;
            int gseg = (L&7) ^ (r&7);
            gll16(&A[(size_t)(m0+r)*K + kbase + gseg*8], &As[(size_t)(wbase + (i<<8))*8]);
        }
        #pragma unroll
        for(int i=0;i<2;i++){
            int L = tid + (i<<8);
            int r = L>>3;
            int gseg = (L&7) ^ (r&7);
            gll16(&W[(size_t)(n0+r)*K + kbase + gseg*8], &Ws[(size_t)(wbase + (i<<8))*8]);
        }
        __syncthreads();
        #pragma unroll
        for(int kk=0; kk<64; kk+=32){
            int sw = ((kk>>3) + quad) ^ (l16&7);
            short8 af[4], bf[2];
            #pragma unroll
            for(int mi=0;mi<4;mi++) af[mi] = *reinterpret_cast<const short8*>(&As[(wm*64+mi*16+l16)*64 + sw*8]);
            #pragma unroll
            for(int ni=0;ni<2;ni++) bf[ni] = *reinterpret_cast<const short8*>(&Ws[(wn*32+ni*16+l16)*64 + sw*8]);
            #pragma unroll
            for(int mi=0;mi<4;mi++)
                #pragma unroll
                for(int ni=0;ni<2;ni++)
                    acc[mi][ni] = __builtin_amdgcn_mfma_f32_16x16x32_bf16(af[mi], bf[ni], acc[mi][ni], 0,0,0);
        }
        __syncthreads();
    }
    #pragma unroll
    for(int mi=0;mi<4;mi++){
        int row = m0 + wm*64 + mi*16 + quad*4;
        #pragma unroll
        for(int ni=0;ni<2;ni++){
            int col = n0 + wn*32 + ni*16 + l16;
            float bv = bias[col];
            float v[4];
            #pragma unroll
            for(int r=0;r<4;r++) v[r] = acc[mi][ni][r] + bv;
            if (EPI==1){
                #pragma unroll
                for(int r=0;r<4;r++){
                    float g = 0.5f*v[r]*(1.f + erff(v[r]*0.70710678f));
                    out[(size_t)(row+r)*N + col] = f2b(g);
                }
            } else if (EPI==2){
                #pragma unroll
                for(int r=0;r<4;r++) xres[(size_t)(row+r)*D_ + col] += v[r];
            } else { // EPI==3
                if (col < 384){
                    #pragma unroll
                    for(int r=0;r<4;r++) out[(size_t)(row+r)*N + col] = f2b(v[r]);
                } else {
                    int hh = (col-384)>>5, dh = (col-384)&31;
                    int bq = row>>9, l = row&511;
                    ushort4 t; t.x=f2b(v[0]); t.y=f2b(v[1]); t.z=f2b(v[2]); t.w=f2b(v[3]);
                    *reinterpret_cast<ushort4*>(&vt[((size_t)(bq*H_+hh)*32 + dh)*512 + l]) = t;
                }
            }
        }
    }
}

// ---------------- flash attention: barrier-free, register-pipelined, single-pass exp ---------
// block = (b,h,q-tile 64), 4 waves x 16 q-rows. K/V/bias direct from global; only P via LDS.
__global__ __launch_bounds__(256) void k_attn(const u16* __restrict__ qkv, const u16* __restrict__ vt,
                                              const u16* __restrict__ bp,
                                              const float* __restrict__ pair_w, const float* __restrict__ pair_b,
                                              const float* __restrict__ relw, const float* __restrict__ relb,
                                              u16* __restrict__ o){
    __shared__ u16 Ps[4][16*88];      // per-wave P round-trip, stride 88 (16B-aligned b128 reads)
    __shared__ float relE[4][68];
    int tid = threadIdx.x;
    int blk = blockIdx.x;
    int b = blk/(H_*8); int rem = blk - b*(H_*8); int h = rem>>3; int qt = rem&7;
    int q0 = qt*64;
    int w = tid>>6, lane = tid&63, quad = lane>>4, l16 = lane&15;
    const float LOG2E = 1.4426950408889634f;
    float pwE  = pair_w[h]*LOG2E;
    float addE = (pair_b[h] + relb[h])*LOG2E;
    relE[w][lane] = relw[h*65 + (lane>64?64:lane)]*LOG2E + addE;
    if (lane==0) relE[w][64] = relw[h*65 + 64]*LOG2E + addE;
    const float scaleE = 0.17677669529663687f*LOG2E;   // 1/sqrt(32) * log2(e)
    short8 qf = *reinterpret_cast<const short8*>(&qkv[(size_t)(b*L_ + q0 + w*16 + l16)*576 + h*32 + quad*8]);
    const u16* kbase = qkv + (size_t)b*L_*576 + 192 + h*32 + quad*8 + (size_t)l16*576;
    const u16* vbase = vt + ((size_t)(b*H_+h)*32 + l16)*512 + quad*8;
    const u16* bbase = bp + (size_t)(((b*8+qt)*4+w)*8)*1024 + (size_t)lane*16;
    f32x4 zero = {0.f,0.f,0.f,0.f};
    f32x4 accO0 = zero, accO1 = zero;
    float l_acc[4] = {0.f,0.f,0.f,0.f};
    // prefetch kt=0
    short8 kf0 = *reinterpret_cast<const short8*>(&kbase[0]);
    short8 kf1 = *reinterpret_cast<const short8*>(&kbase[16*576]);
    short8 kf2 = *reinterpret_cast<const short8*>(&kbase[32*576]);
    short8 kf3 = *reinterpret_cast<const short8*>(&kbase[48*576]);
    uint4 bt0 = *reinterpret_cast<const uint4*>(&bbase[0]);
    uint4 bt1 = *reinterpret_cast<const uint4*>(&bbase[8]);
    for(int kt=0; kt<8; kt++){
        int kn = (kt+1)&7;
        size_t kon = (size_t)kn*64*576;
        // prefetch next K + bias into registers
        short8 nk0 = *reinterpret_cast<const short8*>(&kbase[kon]);
        short8 nk1 = *reinterpret_cast<const short8*>(&kbase[kon+16*576]);
        short8 nk2 = *reinterpret_cast<const short8*>(&kbase[kon+32*576]);
        short8 nk3 = *reinterpret_cast<const short8*>(&kbase[kon+48*576]);
        uint4 nb0 = *reinterpret_cast<const uint4*>(&bbase[(size_t)kn*1024]);
        uint4 nb1 = *reinterpret_cast<const uint4*>(&bbase[(size_t)kn*1024+8]);
        // current V fragments (consumed late)
        short8 vf00 = *reinterpret_cast<const short8*>(&vbase[(size_t)kt*64]);
        short8 vf01 = *reinterpret_cast<const short8*>(&vbase[(size_t)kt*64 + 16*512]);
        short8 vf10 = *reinterpret_cast<const short8*>(&vbase[(size_t)kt*64 + 32]);
        short8 vf11 = *reinterpret_cast<const short8*>(&vbase[(size_t)kt*64 + 16*512 + 32]);
        // S = Q K^T
        f32x4 sv[4];
        sv[0] = __builtin_amdgcn_mfma_f32_16x16x32_bf16(qf, kf0, zero, 0,0,0);
        sv[1] = __builtin_amdgcn_mfma_f32_16x16x32_bf16(qf, kf1, zero, 0,0,0);
        sv[2] = __builtin_amdgcn_mfma_f32_16x16x32_bf16(qf, kf2, zero, 0,0,0);
        sv[3] = __builtin_amdgcn_mfma_f32_16x16x32_bf16(qf, kf3, zero, 0,0,0);
        unsigned bw[8] = {bt0.x,bt0.y,bt0.z,bt0.w,bt1.x,bt1.y,bt1.z,bt1.w};
        bool far = (qt-kt>=2) | (kt-qt>=2);
        float relc = relE[w][qt>kt ? 64 : 0];
        int k0 = kt*64;
        // ni=0,1: exp + P write, then kk=0 PV MFMAs (overlap transcendentals with MFMA)
        #pragma unroll
        for(int ni=0; ni<2; ni++){
            #pragma unroll
            for(int r=0; r<4; r++){
                int j = ni*4+r;
                float bb = (j&1) ? b2f_hi(bw[j>>1]) : b2f_lo(bw[j>>1]);
                float relv;
                if (far) relv = relc;
                else {
                    int dlt = (q0 + w*16 + quad*4 + r) - (k0 + ni*16 + l16);
                    dlt = dlt < -32 ? -32 : (dlt > 32 ? 32 : dlt);
                    relv = relE[w][dlt + 32];
                }
                float pe = exp2f(fmaf(sv[ni][r], scaleE, fmaf(bb, pwE, relv)));
                u16 pr = f2b(pe);
                Ps[w][(quad*4+r)*88 + ni*16 + l16] = pr;
                l_acc[r] += b2f(pr);
            }
        }
        short8 pf0 = *reinterpret_cast<const short8*>(&Ps[w][l16*88 + quad*8]);
        accO0 = __builtin_amdgcn_mfma_f32_16x16x32_bf16(pf0, vf00, accO0, 0,0,0);
        accO1 = __builtin_amdgcn_mfma_f32_16x16x32_bf16(pf0, vf01, accO1, 0,0,0);
        // ni=2,3: exp + P write, then kk=32 PV MFMAs
        #pragma unroll
        for(int ni=2; ni<4; ni++){
            #pragma unroll
            for(int r=0; r<4; r++){
                int j = ni*4+r;
                float bb = (j&1) ? b2f_hi(bw[j>>1]) : b2f_lo(bw[j>>1]);
                float relv;
                if (far) relv = relc;
                else {
                    int dlt = (q0 + w*16 + quad*4 + r) - (k0 + ni*16 + l16);
                    dlt = dlt < -32 ? -32 : (dlt > 32 ? 32 : dlt);
                    relv = relE[w][dlt + 32];
                }
                float pe = exp2f(fmaf(sv[ni][r], scaleE, fmaf(bb, pwE, relv)));
                u16 pr = f2b(pe);
                Ps[w][(quad*4+r)*88 + ni*16 + l16] = pr;
                l_acc[r] += b2f(pr);
            }
        }
        short8 pf1 = *reinterpret_cast<const short8*>(&Ps[w][l16*88 + 32 + quad*8]);
        accO0 = __builtin_amdgcn_mfma_f32_16x16x32_bf16(pf1, vf10, accO0, 0,0,0);
        accO1 = __builtin_amdgcn_mfma_f32_16x16x32_bf16(pf1, vf11, accO1, 0,0,0);
        kf0=nk0; kf1=nk1; kf2=nk2; kf3=nk3; bt0=nb0; bt1=nb1;
    }
    // reduce l across the 16 l16 lanes (butterfly stays within quad group)
    #pragma unroll
    for(int r=0;r<4;r++){
        #pragma unroll
        for(int off=1; off<16; off<<=1) l_acc[r] += __shfl_xor(l_acc[r], off);
    }
    #pragma unroll
    for(int r=0;r<4;r++){
        int qg = q0 + w*16 + quad*4 + r;
        float inv = 1.f / l_acc[r];
        o[(size_t)(b*L_ + qg)*D_ + h*32 + l16]      = f2b(accO0[r] * inv);
        o[(size_t)(b*L_ + qg)*D_ + h*32 + 16 + l16] = f2b(accO1[r] * inv);
    }
}

// ---------------- final projection ----------------
__global__ __launch_bounds__(256) void k_proj(const float* __restrict__ x, const float* __restrict__ pw,
                                              const float* __restrict__ pb, float* __restrict__ out){
    int row  = blockIdx.x*4 + (threadIdx.x>>6);
    int lane = threadIdx.x & 63;
    const float* xr = x + (size_t)row*D_;
    float s0=0.f, s1=0.f;
    #pragma unroll
    for(int j=0;j<3;j++){
        float xv = xr[lane + 64*j];
        s0 += xv * pw[lane + 64*j];
        s1 += xv * pw[192 + lane + 64*j];
    }
    #pragma unroll
    for(int off=32; off; off>>=1){ s0 += __shfl_xor(s0, off); s1 += __shfl_xor(s1, off); }
    if (lane==0){
        out[(size_t)row*2 + 0] = s0 + pb[0];
        out[(size_t)row*2 + 1] = s1 + pb[1];
    }
}

extern "C" void kernel_launch(void* const* d_in, const int* in_sizes, int n_in,
                              void* d_out, int out_size, void* d_ws, size_t ws_size,
                              hipStream_t stream){
    const int*   seq    = (const int*)d_in[0];
    const float* bppm   = (const float*)d_in[2];
    const float* emb    = (const float*)d_in[3];
    const float* pair_w = (const float*)d_in[4];
    const float* pair_b = (const float*)d_in[5];
    const float* relw   = (const float*)d_in[6];
    const float* relb   = (const float*)d_in[7];
    const float* ln1s   = (const float*)d_in[8];
    const float* ln1b   = (const float*)d_in[9];
    const float* qkvw   = (const float*)d_in[10];
    const float* qkvb   = (const float*)d_in[11];
    const float* outw   = (const float*)d_in[12];
    const float* outb   = (const float*)d_in[13];
    const float* ln2s   = (const float*)d_in[14];
    const float* ln2b   = (const float*)d_in[15];
    const float* ff1w   = (const float*)d_in[16];
    const float* ff1b   = (const float*)d_in[17];
    const float* ff2w   = (const float*)d_in[18];
    const float* ff2b   = (const float*)d_in[19];
    const float* projw  = (const float*)d_in[20];
    const float* projb  = (const float*)d_in[21];

    char* ws = (char*)d_ws;
    float* x   = (float*)ws;  ws += (size_t)NR*D_*4;     // f32 residual
    u16*  h    = (u16*)ws;    ws += (size_t)NR*D_*2;     // LN out
    u16*  qkv  = (u16*)ws;    ws += (size_t)NR*576*2;
    u16*  o    = (u16*)ws;    ws += (size_t)NR*D_*2;
    u16*  ff   = (u16*)ws;    ws += (size_t)NR*768*2;
    u16* qkvw_h = (u16*)ws;   ws += (size_t)DEPTH_*576*D_*2;
    u16* outw_h = (u16*)ws;   ws += (size_t)DEPTH_*D_*D_*2;
    u16* ff1w_h = (u16*)ws;   ws += (size_t)DEPTH_*768*D_*2;
    u16* ff2w_h = (u16*)ws;   ws += (size_t)DEPTH_*D_*768*2;
    u16* bp     = (u16*)ws;   ws += (size_t)B_*L_*L_*2;  // permuted bf16 bppm, 16.8 MB
    u16* vt     = (u16*)ws;   ws += (size_t)B_*H_*DH_*L_*2; // 6.3 MB

    {
        int n;
        n = DEPTH_*576*D_/4; k_cvt<<<(n+255)/256, 256, 0, stream>>>(qkvw, qkvw_h, n);
        n = DEPTH_*D_*D_/4;  k_cvt<<<(n+255)/256, 256, 0, stream>>>(outw, outw_h, n);
        n = DEPTH_*768*D_/4; k_cvt<<<(n+255)/256, 256, 0, stream>>>(ff1w, ff1w_h, n);
        n = DEPTH_*D_*768/4; k_cvt<<<(n+255)/256, 256, 0, stream>>>(ff2w, ff2w_h, n);
        k_bprep<<<B_*8*8, 256, 0, stream>>>(bppm, bp);
    }

    k_embed<<<(NR*D_+255)/256, 256, 0, stream>>>(seq, emb, x);
    for(int i=0;i<DEPTH_;i++){
        k_ln<<<NR/4, 256, 0, stream>>>(x, ln1s+i*D_, ln1b+i*D_, h);
        k_gemm<3><<<dim3(576/64, NR/128), 256, 0, stream>>>(h, qkvw_h+(size_t)i*576*D_, qkvb+i*576, qkv, nullptr, vt, NR, 576, D_);
        k_attn<<<B_*H_*8, 256, 0, stream>>>(qkv, vt, bp, pair_w, pair_b, relw, relb, o);
        k_gemm<2><<<dim3(192/64, NR/128), 256, 0, stream>>>(o, outw_h+(size_t)i*D_*D_, outb+i*D_, nullptr, x, nullptr, NR, D_, D_);
        k_ln<<<NR/4, 256, 0, stream>>>(x, ln2s+i*D_, ln2b+i*D_, h);
        k_gemm<1><<<dim3(768/64, NR/128), 256, 0, stream>>>(h, ff1w_h+(size_t)i*768*D_, ff1b+i*768, ff, nullptr, nullptr, NR, 768, D_);
        k_gemm<2><<<dim3(192/64, NR/128), 256, 0, stream>>>(ff, ff2w_h+(size_t)i*D_*768, ff2b+i*D_, nullptr, x, nullptr, NR, D_, 768);
    }
    k_proj<<<NR/4, 256, 0, stream>>>(x, projw, projb, (float*)d_out);
}